// Round 8
// baseline (149.265 us; speedup 1.0000x reference)
//
#include <hip/hip_runtime.h>
#include <math.h>

// Problem constants
#define NB    64
#define L0    128
#define C0    16
#define KW    5
#define NF    8
#define CH1   128
#define CH2   1024
#define CH3   8192
#define NCHUNK 8
#define NS     4
#define SLICE  29
#define TROWS  (SLICE + 4)    // 33
#define Y1R    (SLICE + 8)    // 37
#define STR    (SLICE + 12)   // 41
#define NFH    4
#define NBATCH 2
#define NBG    (NB / NBATCH)  // 32

__device__ __forceinline__ float2 fma2(float2 a, float s, float2 c) {
    return make_float2(fmaf(a.x, s, c.x), fmaf(a.y, s, c.y));
}
__device__ __forceinline__ float2 relu2(float2 a) {
    return make_float2(fmaxf(a.x, 0.f), fmaxf(a.y, 0.f));
}
__device__ __forceinline__ float2 splat2(float s) { return make_float2(s, s); }

// ---------------------------------------------------------------------------
// R8 = R6 kernel exactly (best known config: NBATCH=2, 4 blocks/CU), launched
// 4x as a MEASUREMENT: 3 dummy launches isolate the true marginal (warm)
// duration of the fused kernel from the ~63 us fixed harness overhead
// (268 MB ws-poison fill ~41 us + input restores + gaps) that has masked it
// in the top-5 for five rounds. warm_fused = (total - 93.2)/3.
// ---------------------------------------------------------------------------
__global__ __launch_bounds__(256, 4) void actor_fused_kernel(
    const float* __restrict__ state,   // [64][128][16]
    const float* __restrict__ k1,      // [5][1][128]
    const float* __restrict__ b1,      // [128]
    const float* __restrict__ k2,      // [5][1][1024]
    const float* __restrict__ b2,      // [1024]
    const float* __restrict__ k3,      // [5][1][8192]
    const float* __restrict__ b3,      // [8192]
    const float* __restrict__ W,       // [950272][2]
    float* __restrict__ partials)      // [64][8][4][2]
{
    const int chunk = blockIdx.x;
    const int bg    = blockIdx.y;
    const int slice = blockIdx.z;
    const int t0    = slice * SLICE;
    const int tid   = threadIdx.x;     // 0..255
    const int c3loc = tid >> 1;        // 0..127
    const int fh    = tid & 1;         // 0..1
    const int c3    = chunk * 128 + c3loc;

    __shared__ float  s_state[NBATCH][STR][2];
    __shared__ float2 s_y1[Y1R][16];            // {x,y}=batch
    __shared__ float2 tile[TROWS][128];         // {x,y}=batch, 33 KB

    // ---- stage state ----
    {
        int bb = tid >> 7, lt = tid & 127;
        const float* sp = state + (size_t)(bg * NBATCH + bb) * L0 * C0
                        + (size_t)t0 * C0 + chunk * 2;
        for (int i = lt; i < STR * 2; i += 128) {
            int r = i >> 1, c = i & 1;
            s_state[bb][r][c] = sp[r * C0 + c];
        }
    }
    __syncthreads();

    // ---- conv1 ----
    {
        int bb = tid >> 7, lt = tid & 127;
        for (int i = lt; i < Y1R * 16; i += 128) {
            int r = i >> 4, jloc = i & 15;
            int j = chunk * 16 + jloc;
            int cloc = jloc >> 3;
            float acc = b1[j];
#pragma unroll
            for (int k = 0; k < KW; ++k)
                acc = fmaf(s_state[bb][r + k][cloc], k1[k * CH1 + j], acc);
            ((float*)&s_y1[r][jloc])[bb] = fmaxf(acc, 0.f);
        }
    }
    __syncthreads();

    // ---- conv2 ----
    {
        int c = tid & 127, h = tid >> 7;
        int m = chunk * 128 + c;
        int jloc = c >> 3;
        float kk[KW], b2v = b2[m];
#pragma unroll
        for (int k = 0; k < KW; ++k) kk[k] = k2[k * CH2 + m];
        int r0 = h ? 17 : 0, r1 = h ? TROWS : 17;
        float2 u0 = s_y1[r0 + 0][jloc];
        float2 u1 = s_y1[r0 + 1][jloc];
        float2 u2 = s_y1[r0 + 2][jloc];
        float2 u3 = s_y1[r0 + 3][jloc];
        for (int r = r0; r < r1; ++r) {
            float2 u4 = s_y1[r + 4][jloc];
            float2 acc = splat2(b2v);
            acc = fma2(u0, kk[0], acc);
            acc = fma2(u1, kk[1], acc);
            acc = fma2(u2, kk[2], acc);
            acc = fma2(u3, kk[3], acc);
            acc = fma2(u4, kk[4], acc);
            tile[r][c] = relu2(acc);
            u0 = u1; u1 = u2; u2 = u3; u3 = u4;
        }
    }

    // ---- conv3 weights + bias ----
    float kw[KW][NFH], bv[NFH];
#pragma unroll
    for (int k = 0; k < KW; ++k)
#pragma unroll
        for (int f = 0; f < NFH; ++f)
            kw[k][f] = k3[k * CH3 + c3 * NF + fh * NFH + f];
#pragma unroll
    for (int f = 0; f < NFH; ++f)
        bv[f] = b3[c3 * NF + fh * NFH + f];

    __syncthreads();   // tile ready

    // ---- main loop: conv3 + relu + dense, batch-pair float2 ----
    float2 axv = splat2(0.f), ayv = splat2(0.f);

    const float4* __restrict__ wp =
        (const float4*)W + (size_t)t0 * 4096 + (size_t)c3 * 4 + fh * 2;
    float4 cq0 = wp[0];
    float4 cq1 = wp[1];

    float2 tw0 = tile[0][c3loc];
    float2 tw1 = tile[1][c3loc];
    float2 tw2 = tile[2][c3loc];
    float2 tw3 = tile[3][c3loc];

    for (int t = 0; t < SLICE; ++t) {
        float2 tw4 = tile[t + 4][c3loc];            // one ds_read_b64
        const float4* wn = wp + (t < SLICE - 1 ? 4096 : 0);  // prefetch t+1
        float4 nq0 = wn[0];
        float4 nq1 = wn[1];

        float2 v[NFH];
#pragma unroll
        for (int f = 0; f < NFH; ++f) {
            float2 a = splat2(bv[f]);
            a = fma2(tw0, kw[0][f], a);
            a = fma2(tw1, kw[1][f], a);
            a = fma2(tw2, kw[2][f], a);
            a = fma2(tw3, kw[3][f], a);
            a = fma2(tw4, kw[4][f], a);
            v[f] = relu2(a);
        }

        axv = fma2(v[0], cq0.x, axv); ayv = fma2(v[0], cq0.y, ayv);
        axv = fma2(v[1], cq0.z, axv); ayv = fma2(v[1], cq0.w, ayv);
        axv = fma2(v[2], cq1.x, axv); ayv = fma2(v[2], cq1.y, ayv);
        axv = fma2(v[3], cq1.z, axv); ayv = fma2(v[3], cq1.w, ayv);

        wp = wn; cq0 = nq0; cq1 = nq1;
        tw0 = tw1; tw1 = tw2; tw2 = tw3; tw3 = tw4;
    }

    // ---- reductions ----
#pragma unroll
    for (int d = 32; d >= 1; d >>= 1) {
        axv.x += __shfl_down(axv.x, d, 64); ayv.x += __shfl_down(ayv.x, d, 64);
        axv.y += __shfl_down(axv.y, d, 64); ayv.y += __shfl_down(ayv.y, d, 64);
    }
    __shared__ float red[4][NBATCH][2];
    int wave = tid >> 6, lane = tid & 63;
    if (lane == 0) {
        red[wave][0][0] = axv.x; red[wave][0][1] = ayv.x;
        red[wave][1][0] = axv.y; red[wave][1][1] = ayv.y;
    }
    __syncthreads();
    if (tid < NBATCH * 2) {
        int bb = tid >> 1, a = tid & 1;
        float s = (red[0][bb][a] + red[1][bb][a]) + (red[2][bb][a] + red[3][bb][a]);
        int b = bg * NBATCH + bb;
        partials[(((size_t)b * NCHUNK + chunk) * NS + slice) * 2 + a] = s;
    }
}

// ---------------------------------------------------------------------------
__global__ __launch_bounds__(128) void finish_kernel(
    const float* __restrict__ partials,  // [64][8][4][2]
    const float* __restrict__ bd,        // [2]
    float* __restrict__ out)             // [64][2]
{
    int i = threadIdx.x;
    int b = i >> 1, a = i & 1;
    float s = bd[a];
#pragma unroll
    for (int p = 0; p < NCHUNK * NS; ++p)
        s += partials[((size_t)b * NCHUNK * NS + p) * 2 + a];
    out[b * 2 + a] = tanhf(s);
}

extern "C" void kernel_launch(void* const* d_in, const int* in_sizes, int n_in,
                              void* d_out, int out_size, void* d_ws, size_t ws_size,
                              hipStream_t stream) {
    const float* state = (const float*)d_in[0];
    const float* k1    = (const float*)d_in[1];
    const float* b1    = (const float*)d_in[2];
    const float* k2    = (const float*)d_in[3];
    const float* b2    = (const float*)d_in[4];
    const float* k3    = (const float*)d_in[5];
    const float* b3    = (const float*)d_in[6];
    const float* W     = (const float*)d_in[7];
    const float* bd    = (const float*)d_in[8];
    float* out = (float*)d_out;

    float* partials = (float*)d_ws;                       // real result
    float* dummy1   = (float*)((char*)d_ws + (1 << 20));  // measurement-only
    float* dummy2   = (float*)((char*)d_ws + (2 << 20));
    float* dummy3   = (float*)((char*)d_ws + (3 << 20));

    dim3 grid(NCHUNK, NBG, NS);
    // MEASUREMENT: 3 extra identical launches (cold->warm). Marginal cost of
    // each repeat = true fused-kernel duration, cleanly separated from the
    // fixed ~63 us harness overhead. Last launch writes the real partials.
    actor_fused_kernel<<<grid, 256, 0, stream>>>(state, k1, b1, k2, b2, k3, b3, W, dummy1);
    actor_fused_kernel<<<grid, 256, 0, stream>>>(state, k1, b1, k2, b2, k3, b3, W, dummy2);
    actor_fused_kernel<<<grid, 256, 0, stream>>>(state, k1, b1, k2, b2, k3, b3, W, dummy3);
    actor_fused_kernel<<<grid, 256, 0, stream>>>(state, k1, b1, k2, b2, k3, b3, W, partials);

    finish_kernel<<<1, 128, 0, stream>>>(partials, bd, out);
}

// Round 9
// 89.278 us; speedup vs baseline: 1.6719x; 1.6719x over previous
//
#include <hip/hip_runtime.h>
#include <math.h>

// Problem constants
#define NB    64
#define L0    128
#define C0    16
#define KW    5
#define NF    8
#define CH1   128
#define CH2   1024
#define CH3   8192
#define NCHUNK 8
#define NS     4
#define SLICE  29
#define TROWS  (SLICE + 4)    // 33
#define Y1R    (SLICE + 8)    // 37
#define STR    (SLICE + 12)   // 41
#define NFH    4
#define NBATCH 4              // batches per block (R5 config: 2 blocks/CU)
#define NBG    (NB / NBATCH)  // 16

typedef float v4f __attribute__((ext_vector_type(4)));

__device__ __forceinline__ v4f splat(float s) { return (v4f){s, s, s, s}; }
// a*s + c, elementwise -> v_pk_fma_f32 pairs on gfx950
__device__ __forceinline__ v4f vfma(v4f a, float s, v4f c) {
    return __builtin_elementwise_fma(a, splat(s), c);
}
__device__ __forceinline__ v4f vrelu(v4f a) {
    return __builtin_elementwise_max(a, splat(0.f));
}

// ---------------------------------------------------------------------------
// Fused conv1+conv2+conv3+dense. NBATCH=4, packed-fp32 math, unroll-2 main
// loop with ring-2 W prefetch (refill-after-consume, consumed one full
// double-iter later) and double-row ds prefetch at the top of each double-iter.
// Grid (chunk=8, bg=16, slice=4) = 512 blocks, 2 blocks/CU (78 KB LDS).
// R8 measurement: warm fused = 18.7 us vs ~8.5 us scalar issue floor; packed
// fp32 halves the issue floor; NBATCH=4 halves per-CU W-L2 demand vs R6.
// ---------------------------------------------------------------------------
__global__ __launch_bounds__(256, 2) void actor_fused_kernel(
    const float* __restrict__ state,   // [64][128][16]
    const float* __restrict__ k1,      // [5][1][128]
    const float* __restrict__ b1,      // [128]
    const float* __restrict__ k2,      // [5][1][1024]
    const float* __restrict__ b2,      // [1024]
    const float* __restrict__ k3,      // [5][1][8192]
    const float* __restrict__ b3,      // [8192]
    const float* __restrict__ W,       // [950272][2]
    float* __restrict__ partials)      // [64][8][4][2]
{
    const int chunk = blockIdx.x;      // 0..7
    const int bg    = blockIdx.y;      // 0..15
    const int slice = blockIdx.z;      // 0..3
    const int t0    = slice * SLICE;
    const int tid   = threadIdx.x;     // 0..255
    const int c3loc = tid >> 1;        // 0..127
    const int fh    = tid & 1;         // 0..1
    const int c3    = chunk * 128 + c3loc;

    __shared__ float s_state[NBATCH][STR][2];   // 1.3 KB
    __shared__ v4f   s_y1[Y1R][16];             // lanes = batches, 9.25 KB
    __shared__ v4f   tile[TROWS][128];          // lanes = batches, 66 KB

    // ---- stage state: wave bb = tid>>6 owns batch bg*4+bb ----
    {
        int bb = tid >> 6, lt = tid & 63;
        const float* sp = state + (size_t)(bg * NBATCH + bb) * L0 * C0
                        + (size_t)t0 * C0 + chunk * 2;
        for (int i = lt; i < STR * 2; i += 64) {
            int r = i >> 1, c = i & 1;
            s_state[bb][r][c] = sp[r * C0 + c];
        }
    }
    __syncthreads();

    // ---- conv1: wave bb writes component bb of s_y1 ----
    {
        int bb = tid >> 6, lt = tid & 63;
        for (int i = lt; i < Y1R * 16; i += 64) {
            int r = i >> 4, jloc = i & 15;
            int j = chunk * 16 + jloc;
            int cloc = jloc >> 3;
            float acc = b1[j];
#pragma unroll
            for (int k = 0; k < KW; ++k)
                acc = fmaf(s_state[bb][r + k][cloc], k1[k * CH1 + j], acc);
            ((float*)&s_y1[r][jloc])[bb] = fmaxf(acc, 0.f);
        }
    }
    __syncthreads();

    // ---- conv2: col c = tid&127, row-half h = tid>>7, all 4 batches packed ----
    {
        int c = tid & 127, h = tid >> 7;
        int m = chunk * 128 + c;
        int jloc = c >> 3;
        float kk[KW], b2v = b2[m];
#pragma unroll
        for (int k = 0; k < KW; ++k) kk[k] = k2[k * CH2 + m];
        int r0i = h ? 17 : 0, r1i = h ? TROWS : 17;
        v4f u0 = s_y1[r0i + 0][jloc];
        v4f u1 = s_y1[r0i + 1][jloc];
        v4f u2 = s_y1[r0i + 2][jloc];
        v4f u3 = s_y1[r0i + 3][jloc];
        for (int r = r0i; r < r1i; ++r) {
            v4f u4 = s_y1[r + 4][jloc];
            v4f acc = splat(b2v);
            acc = vfma(u0, kk[0], acc);
            acc = vfma(u1, kk[1], acc);
            acc = vfma(u2, kk[2], acc);
            acc = vfma(u3, kk[3], acc);
            acc = vfma(u4, kk[4], acc);
            tile[r][c] = vrelu(acc);
            u0 = u1; u1 = u2; u2 = u3; u3 = u4;
        }
    }

    // ---- conv3 weights + bias (scalar, register-resident) ----
    float kw[KW][NFH], bv[NFH];
#pragma unroll
    for (int k = 0; k < KW; ++k)
#pragma unroll
        for (int f = 0; f < NFH; ++f)
            kw[k][f] = k3[k * CH3 + c3 * NF + fh * NFH + f];
#pragma unroll
    for (int f = 0; f < NFH; ++f)
        bv[f] = b3[c3 * NF + fh * NFH + f];

    __syncthreads();   // tile ready

    // ---- main loop: unroll-2, ring-2 W slots, double-row ds prefetch ----
    v4f accx = splat(0.f), accy = splat(0.f);

    const v4f* __restrict__ wb =
        (const v4f*)W + (size_t)t0 * 4096 + (size_t)c3 * 4 + fh * 2;
    v4f qa0 = wb[0],    qa1 = wb[1];       // W[t]   (even slot)
    v4f qb0 = wb[4096], qb1 = wb[4097];    // W[t+1] (odd slot)

    v4f r0 = tile[0][c3loc], r1 = tile[1][c3loc], r2 = tile[2][c3loc],
        r3 = tile[3][c3loc], r4 = tile[4][c3loc], rn = tile[5][c3loc];

#define SUBITER(A0, A1, A2, A3, A4, Q0, Q1)                                   \
    {                                                                          \
        v4f v0 = splat(bv[0]), v1 = splat(bv[1]);                              \
        v4f v2 = splat(bv[2]), v3 = splat(bv[3]);                              \
        v0 = vfma(A0, kw[0][0], v0); v1 = vfma(A0, kw[0][1], v1);              \
        v2 = vfma(A0, kw[0][2], v2); v3 = vfma(A0, kw[0][3], v3);              \
        v0 = vfma(A1, kw[1][0], v0); v1 = vfma(A1, kw[1][1], v1);              \
        v2 = vfma(A1, kw[1][2], v2); v3 = vfma(A1, kw[1][3], v3);              \
        v0 = vfma(A2, kw[2][0], v0); v1 = vfma(A2, kw[2][1], v1);              \
        v2 = vfma(A2, kw[2][2], v2); v3 = vfma(A2, kw[2][3], v3);              \
        v0 = vfma(A3, kw[3][0], v0); v1 = vfma(A3, kw[3][1], v1);              \
        v2 = vfma(A3, kw[3][2], v2); v3 = vfma(A3, kw[3][3], v3);              \
        v0 = vfma(A4, kw[4][0], v0); v1 = vfma(A4, kw[4][1], v1);              \
        v2 = vfma(A4, kw[4][2], v2); v3 = vfma(A4, kw[4][3], v3);              \
        v0 = vrelu(v0); v1 = vrelu(v1); v2 = vrelu(v2); v3 = vrelu(v3);        \
        accx = vfma(v0, Q0.x, accx); accy = vfma(v0, Q0.y, accy);              \
        accx = vfma(v1, Q0.z, accx); accy = vfma(v1, Q0.w, accy);              \
        accx = vfma(v2, Q1.x, accx); accy = vfma(v2, Q1.y, accy);              \
        accx = vfma(v3, Q1.z, accx); accy = vfma(v3, Q1.w, accy);              \
    }

    for (int t = 0; t < SLICE - 1; t += 2) {   // t = 0,2,...,26
        // ds prefetch for the NEXT double-iter (consumed ~130 inst later)
        v4f na = tile[t + 6][c3loc];
        int tb = (t + 7 < TROWS) ? (t + 7) : (TROWS - 1);
        v4f nb = tile[tb][c3loc];

        // even sub-iter: rows t..t+4, W[t]; refill slot A with W[t+2]
        SUBITER(r0, r1, r2, r3, r4, qa0, qa1);
        qa0 = wb[(size_t)(t + 2) * 4096];
        qa1 = wb[(size_t)(t + 2) * 4096 + 1];

        // odd sub-iter: rows t+1..t+5, W[t+1]; refill slot B with W[t+3]
        SUBITER(r1, r2, r3, r4, rn, qb0, qb1);
        int tp = (t + 3 < SLICE) ? (t + 3) : (SLICE - 1);
        qb0 = wb[(size_t)tp * 4096];
        qb1 = wb[(size_t)tp * 4096 + 1];

        // shift window by 2
        r0 = r2; r1 = r3; r2 = r4; r3 = rn; r4 = na; rn = nb;
    }
    // tail sub-iter t = 28: rows 28..32, W[28] (slot A)
    SUBITER(r0, r1, r2, r3, r4, qa0, qa1);
#undef SUBITER

    // ---- reductions: 4 batches x 2 outputs ----
    float ax[NBATCH] = {accx.x, accx.y, accx.z, accx.w};
    float ay[NBATCH] = {accy.x, accy.y, accy.z, accy.w};
#pragma unroll
    for (int bb = 0; bb < NBATCH; ++bb)
#pragma unroll
        for (int d = 32; d >= 1; d >>= 1) {
            ax[bb] += __shfl_down(ax[bb], d, 64);
            ay[bb] += __shfl_down(ay[bb], d, 64);
        }
    __shared__ float red[4][NBATCH][2];
    int wave = tid >> 6, lane = tid & 63;
    if (lane == 0) {
#pragma unroll
        for (int bb = 0; bb < NBATCH; ++bb) {
            red[wave][bb][0] = ax[bb];
            red[wave][bb][1] = ay[bb];
        }
    }
    __syncthreads();
    if (tid < NBATCH * 2) {
        int bb = tid >> 1, a = tid & 1;
        float s = (red[0][bb][a] + red[1][bb][a]) + (red[2][bb][a] + red[3][bb][a]);
        int b = bg * NBATCH + bb;
        partials[(((size_t)b * NCHUNK + chunk) * NS + slice) * 2 + a] = s;
    }
}

// ---------------------------------------------------------------------------
__global__ __launch_bounds__(128) void finish_kernel(
    const float* __restrict__ partials,  // [64][8][4][2]
    const float* __restrict__ bd,        // [2]
    float* __restrict__ out)             // [64][2]
{
    int i = threadIdx.x;
    int b = i >> 1, a = i & 1;
    float s = bd[a];
#pragma unroll
    for (int p = 0; p < NCHUNK * NS; ++p)
        s += partials[((size_t)b * NCHUNK * NS + p) * 2 + a];
    out[b * 2 + a] = tanhf(s);
}

extern "C" void kernel_launch(void* const* d_in, const int* in_sizes, int n_in,
                              void* d_out, int out_size, void* d_ws, size_t ws_size,
                              hipStream_t stream) {
    const float* state = (const float*)d_in[0];
    const float* k1    = (const float*)d_in[1];
    const float* b1    = (const float*)d_in[2];
    const float* k2    = (const float*)d_in[3];
    const float* b2    = (const float*)d_in[4];
    const float* k3    = (const float*)d_in[5];
    const float* b3    = (const float*)d_in[6];
    const float* W     = (const float*)d_in[7];
    const float* bd    = (const float*)d_in[8];
    float* out = (float*)d_out;

    float* partials = (float*)d_ws;   // 64*8*4*2 fp32 = 16 KB

    dim3 grid(NCHUNK, NBG, NS);
    actor_fused_kernel<<<grid, 256, 0, stream>>>(
        state, k1, b1, k2, b2, k3, b3, W, partials);

    finish_kernel<<<1, 128, 0, stream>>>(partials, bd, out);
}